// Round 3
// baseline (622.654 us; speedup 1.0000x reference)
//
#include <hip/hip_runtime.h>
#include <hip/hip_bf16.h>

#define NQ     14
#define DIM    16384
#define NLAYER 16
#define BATCH  512
#define NT     1024

// bijective LDS swizzle: XOR bits 5..9 into bits 0..4 (bank-conflict killer)
__device__ __forceinline__ int POS(int x){ return x ^ ((x >> 5) & 31); }

__device__ __forceinline__ float bf2f(unsigned int u16){
  union { unsigned int i; float f; } v; v.i = u16 << 16; return v.f;
}

// theta accessor: harness may deliver float inputs as bf16; branch on sniffed flag
__device__ __forceinline__ float thv(const void* th, int i, bool b16){
  return b16 ? bf2f(((const unsigned short*)th)[i]) : ((const float*)th)[i];
}

// Composed CNOT-ring source map: psi_out[x] = psi_in[srcF(x)].
// cnot(k, (k+1)%14): control qubit k = index bit (13-k), target bit 13-((k+1)%14).
// Applied w=0..13 in order -> src = m0(m1(...m13(x))); linear over GF(2).
__device__ int srcF(int x){
  int v = x;
  #pragma unroll
  for (int k = 13; k >= 0; --k){
    int tb = 13 - ((k + 1) % 14);
    v ^= ((v >> (13 - k)) & 1) << tb;
  }
  return v;
}

__device__ __forceinline__ void rot2(float2& a0, float2& a1, float c, float s){
  float2 t0 = a0, t1 = a1;
  a0 = make_float2(c*t0.x - s*t1.x, c*t0.y - s*t1.y);
  a1 = make_float2(s*t0.x + c*t1.x, s*t0.y + c*t1.y);
}

__device__ __forceinline__ float2 cmulph(float2 a, float2 ch, float2 cl){
  // a * (ch.x + i ch.y) * (cl.x + i cl.y)
  float cc = ch.x*cl.x - ch.y*cl.y;
  float ss = ch.x*cl.y + ch.y*cl.x;
  return make_float2(a.x*cc - a.y*ss, a.x*ss + a.y*cc);
}

__global__ __launch_bounds__(NT)
void qnn_circuit(const void* __restrict__ zraw,
                 const void* __restrict__ theta,
                 float* __restrict__ out)
{
  __shared__ float2 S[DIM];                                   // 128 KiB state
  __shared__ float2 ph0H[128], ph0L[128], ph2H[128], ph2L[128]; // RZ cos/sin
  __shared__ float  csT[28];                                  // RY cos/sin
  __shared__ int    srcH[128], srcL[128];                     // CNOT perm tables
  __shared__ float  red[16*5];

  const int t = threadIdx.x;
  const int b = blockIdx.x;

  // ---- sniff theta dtype: bf16 vs float32 ----
  // bf16 randn: low-half exponent in [100,140] ~always; f32 mantissa bits: ~16%.
  int pred = 0;
  if (t < 336){
    unsigned int w  = ((const unsigned int*)theta)[t];  // 1344 B, in-bounds either way
    unsigned int lo = w & 0xffffu;
    unsigned int e  = (lo >> 7) & 0xffu;
    pred = (e >= 100 && e <= 140) || (lo == 0);
  }
  const bool th_b16 = (__syncthreads_count(pred) > 250);

  // ---- sniff z format: bf16 (re,im) pairs  vs  float32 real-part-only ----
  // Both are 33.55 MB raw (npz pins 2-byte-per-... or f32-real). For bf16 pairs
  // the low half of each word is a bf16 with exponent in [88,140] (~100%);
  // for f32 the low half is mantissa bits (~20% pass).
  pred = 0;
  if (t < 256){
    unsigned int w  = ((const unsigned int*)zraw)[t];
    unsigned int lo = w & 0xffffu;
    unsigned int e  = (lo >> 7) & 0xffu;
    pred = (e >= 88 && e <= 140) || (lo == 0);
  }
  const bool z_b16 = (__syncthreads_count(pred) > 160);

  if (t < 128){ srcH[t] = srcF(t << 7); srcL[t] = srcF(t); }

  // ---- load z -> LDS (swizzled), per sniffed format ----
  if (z_b16){
    const uint4* zb = (const uint4*)((const unsigned short*)zraw + (size_t)b * (DIM * 2));
    #pragma unroll
    for (int jj = 0; jj < 4; ++jj){
      int x4 = t + NT * jj;
      uint4 w = zb[x4];
      int xb = x4 * 4;
      S[POS(xb+0)] = make_float2(bf2f(w.x & 0xffffu), bf2f(w.x >> 16));
      S[POS(xb+1)] = make_float2(bf2f(w.y & 0xffffu), bf2f(w.y >> 16));
      S[POS(xb+2)] = make_float2(bf2f(w.z & 0xffffu), bf2f(w.z >> 16));
      S[POS(xb+3)] = make_float2(bf2f(w.w & 0xffffu), bf2f(w.w >> 16));
    }
  } else {
    const float4* zf = (const float4*)((const float*)zraw + (size_t)b * DIM);
    #pragma unroll
    for (int jj = 0; jj < 4; ++jj){
      int x4 = t + NT * jj;
      float4 w = zf[x4];
      int xb = x4 * 4;
      S[POS(xb+0)] = make_float2(w.x, 0.f);
      S[POS(xb+1)] = make_float2(w.y, 0.f);
      S[POS(xb+2)] = make_float2(w.z, 0.f);
      S[POS(xb+3)] = make_float2(w.w, 0.f);
    }
  }
  __syncthreads();

  float2 a[16];

  for (int l = 0; l < NLAYER; ++l){
    const int thb = l * 42;

    // ---- prep: RZ phase tables (H = qubits 0..6 <-> x[13:7], L = 7..13) + RY angles
    if (t < 512){
      int grp = t >> 7, idx = t & 127;
      int tz = thb + ((grp >= 2) ? 28 : 0);
      float ph = 0.f;
      if ((grp & 1) == 0){
        #pragma unroll
        for (int w = 0; w < 7; ++w)
          ph += (((idx >> (6 - w)) & 1) ? 0.5f : -0.5f) * thv(theta, tz + w, th_b16);
      } else {
        #pragma unroll
        for (int w = 7; w < 14; ++w)
          ph += (((idx >> (13 - w)) & 1) ? 0.5f : -0.5f) * thv(theta, tz + w, th_b16);
      }
      float sn, cs; sincosf(ph, &sn, &cs);
      float2 v = make_float2(cs, sn);
      if      (grp == 0) ph0H[idx] = v;
      else if (grp == 1) ph0L[idx] = v;
      else if (grp == 2) ph2H[idx] = v;
      else               ph2L[idx] = v;
    } else if (t < 512 + 14){
      int q = t - 512;
      float sn, cs; sincosf(0.5f * thv(theta, thb + 14 + q, th_b16), &sn, &cs);
      csT[2*q] = cs; csT[2*q+1] = sn;
    }

    // ---- P1: gather (undo previous CNOT ring) + RZ0 + RY qubits 0..3 ----
    // thread t holds x = t + 1024*j  (j = x bits 13..10)
    if (l == 0){
      #pragma unroll
      for (int j = 0; j < 16; ++j) a[j] = S[POS(t + NT*j)];
    } else {
      int sl = srcL[t & 127];
      #pragma unroll
      for (int j = 0; j < 16; ++j)
        a[j] = S[POS(srcH[(t >> 7) + 8*j] ^ sl)];
    }
    __syncthreads();   // gathers done; tables visible

    {
      float2 cl = ph0L[t & 127];
      #pragma unroll
      for (int j = 0; j < 16; ++j)
        a[j] = cmulph(a[j], ph0H[(t >> 7) + 8*j], cl);
    }
    #pragma unroll
    for (int q = 0; q < 4; ++q){
      float c = csT[2*q], s = csT[2*q+1];
      int m = 8 >> q;
      #pragma unroll
      for (int j = 0; j < 16; ++j){
        if (j & m) continue;
        rot2(a[j], a[j | m], c, s);
      }
    }
    #pragma unroll
    for (int j = 0; j < 16; ++j) S[POS(t + NT*j)] = a[j];
    __syncthreads();

    // ---- P2: RY qubits 4..7 (x bits 9..6) ----
    {
      int base = ((t >> 6) << 10) | (t & 63);
      #pragma unroll
      for (int j = 0; j < 16; ++j) a[j] = S[POS(base | (j << 6))];
      #pragma unroll
      for (int q = 0; q < 4; ++q){
        float c = csT[2*(4+q)], s = csT[2*(4+q)+1];
        int m = 8 >> q;
        #pragma unroll
        for (int j = 0; j < 16; ++j){
          if (j & m) continue;
          rot2(a[j], a[j | m], c, s);
        }
      }
      #pragma unroll
      for (int j = 0; j < 16; ++j) S[POS(base | (j << 6))] = a[j];
    }
    __syncthreads();

    // ---- P3: RY qubits 8..10 (x bits 5..3) ----
    #pragma unroll
    for (int it = 0; it < 2; ++it){
      int s4 = t + NT * it;
      int base = (s4 & 7) | (((s4 >> 3) & 7) << 8) | (((s4 >> 6) & 3) << 6)
               | (((s4 >> 8) & 7) << 11);
      #pragma unroll
      for (int j = 0; j < 8; ++j) a[j] = S[POS(base | (j << 3))];
      #pragma unroll
      for (int q = 0; q < 3; ++q){
        float c = csT[2*(8+q)], s = csT[2*(8+q)+1];
        int m = 4 >> q;
        #pragma unroll
        for (int j = 0; j < 8; ++j){
          if (j & m) continue;
          rot2(a[j], a[j | m], c, s);
        }
      }
      #pragma unroll
      for (int j = 0; j < 8; ++j) S[POS(base | (j << 3))] = a[j];
    }
    __syncthreads();

    // ---- P4: RY qubits 11..13 (x bits 2..0) + RZ2 ----
    #pragma unroll
    for (int it = 0; it < 2; ++it){
      int s4 = t + NT * it;
      int base = ((s4 & 63) << 5) | (((s4 >> 6) & 3) << 3) | (((s4 >> 8) & 7) << 11);
      #pragma unroll
      for (int j = 0; j < 8; ++j) a[j] = S[POS(base | j)];
      #pragma unroll
      for (int q = 0; q < 3; ++q){
        float c = csT[2*(11+q)], s = csT[2*(11+q)+1];
        int m = 4 >> q;
        #pragma unroll
        for (int j = 0; j < 8; ++j){
          if (j & m) continue;
          rot2(a[j], a[j | m], c, s);
        }
      }
      #pragma unroll
      for (int j = 0; j < 8; ++j){
        int x = base | j;
        a[j] = cmulph(a[j], ph2H[x >> 7], ph2L[x & 127]);
      }
      #pragma unroll
      for (int j = 0; j < 8; ++j) S[POS(base | j)] = a[j];
    }
    __syncthreads();
  }

  // ---- measurement (final CNOT ring still pending -> gather via src) ----
  float z0=0.f, z1=0.f, x0s=0.f, x1s=0.f, y0s=0.f;
  {
    int sl = srcL[t & 127];
    #pragma unroll
    for (int j = 0; j < 16; ++j)
      a[j] = S[POS(srcH[(t >> 7) + 8*j] ^ sl)];

    #pragma unroll
    for (int j = 0; j < 16; ++j){
      float pw = a[j].x*a[j].x + a[j].y*a[j].y;
      z0 += (j & 8) ? -pw : pw;     // qubit0 = x bit13 = j bit3
      z1 += (j & 4) ? -pw : pw;     // qubit1 = x bit12 = j bit2
    }
    #pragma unroll
    for (int j = 0; j < 8; ++j){
      float2 p0 = a[j], p1 = a[j+8];
      x0s += 2.f*(p0.x*p1.x + p0.y*p1.y);
      y0s += 2.f*(p0.x*p1.y - p0.y*p1.x);
    }
    #pragma unroll
    for (int j = 0; j < 16; ++j){
      if (j & 4) continue;
      float2 p0 = a[j], p1 = a[j|4];
      x1s += 2.f*(p0.x*p1.x + p0.y*p1.y);
    }
  }
  #pragma unroll
  for (int o = 32; o >= 1; o >>= 1){
    z0  += __shfl_down(z0,  o, 64);
    z1  += __shfl_down(z1,  o, 64);
    x0s += __shfl_down(x0s, o, 64);
    x1s += __shfl_down(x1s, o, 64);
    y0s += __shfl_down(y0s, o, 64);
  }
  int wid = t >> 6, lane = t & 63;
  if (lane == 0){
    red[wid*5+0]=z0; red[wid*5+1]=z1; red[wid*5+2]=x0s; red[wid*5+3]=x1s; red[wid*5+4]=y0s;
  }
  __syncthreads();
  if (t < 5){
    float sum = 0.f;
    #pragma unroll
    for (int w = 0; w < 16; ++w) sum += red[w*5 + t];
    out[1 + b*5 + t] = sum;
  }
}

__global__ __launch_bounds__(512)
void qnn_loss(const int* __restrict__ y, float* __restrict__ out)
{
  __shared__ float red[8];
  int t = threadIdx.x;   // one thread per batch element
  const float* o = out + 1 + t*5;
  float o0=o[0], o1=o[1], o2=o[2], o3=o[3], o4=o[4];
  float m = fmaxf(fmaxf(fmaxf(o0,o1), fmaxf(o2,o3)), o4);
  float sum = expf(o0-m)+expf(o1-m)+expf(o2-m)+expf(o3-m)+expf(o4-m);
  float lse = m + logf(sum);
  int yi = y[t]; yi = yi < 0 ? 0 : (yi > 4 ? 4 : yi);
  float lb = lse - o[yi];

  #pragma unroll
  for (int ofs = 32; ofs >= 1; ofs >>= 1) lb += __shfl_down(lb, ofs, 64);
  if ((t & 63) == 0) red[t >> 6] = lb;
  __syncthreads();
  if (t == 0){
    float s = 0.f;
    #pragma unroll
    for (int w = 0; w < 8; ++w) s += red[w];
    out[0] = s / (float)BATCH;
  }
}

extern "C" void kernel_launch(void* const* d_in, const int* in_sizes, int n_in,
                              void* d_out, int out_size, void* d_ws, size_t ws_size,
                              hipStream_t stream)
{
  const void* z     = d_in[0];            // bf16 (re,im) pairs OR f32 real (sniffed)
  const void* theta = d_in[1];            // bf16 or f32 (sniffed)
  const int*  y     = (const int*)d_in[2];
  float*      out   = (float*)d_out;

  qnn_circuit<<<BATCH, NT, 0, stream>>>(z, theta, out);
  qnn_loss<<<1, 512, 0, stream>>>(y, out);
}